// Round 16
// baseline (1456.826 us; speedup 1.0000x reference)
//
#include <hip/hip_runtime.h>
#include <math.h>

#define NB 4
#define NW 24
#define H 512
#define H2 1024
#define H5 2560
#define NCELL 300   // n*(n+1)/2 valid cells per batch
#define NEED_BYTES ((size_t)72<<20)

// Private fallback workspace: allocated ONCE at library load (outside
// kernel_launch, so graph capture never sees the hipMalloc). d_ws proved too
// small in round 1 (44.9MB layout corrupted adjacent harness allocations).
static float* g_buf = nullptr;
__attribute__((constructor)) static void dio_alloc_ws(){
  (void)hipMalloc((void**)&g_buf, NEED_BYTES);
}

typedef __attribute__((ext_vector_type(8))) short bf16x8;   // 8 bf16 (4 VGPRs)
typedef __attribute__((ext_vector_type(4))) float f32x4;
typedef unsigned short ushort_t;

__device__ __forceinline__ int coff(int l){ return l*NW - (l*(l-1))/2; }
__device__ __forceinline__ float sigm(float x){ return 1.f/(1.f+__expf(-x)); }
__device__ __forceinline__ float ftanh(float x){ return 1.f - 2.f/(__expf(2.f*x)+1.f); }

__device__ __forceinline__ ushort_t f2b(float x){  // fp32 -> bf16 RNE
  unsigned int u = __float_as_uint(x);
  u += 0x7FFF + ((u>>16)&1);
  return (ushort_t)(u>>16);
}
__device__ __forceinline__ float b2f(ushort_t h){
  return __uint_as_float(((unsigned int)h)<<16);
}
// split-bf16: x ~= hi + lo with effective ~2^-17 relative error
__device__ __forceinline__ void split_store(ushort_t* __restrict__ ph,
                                            ushort_t* __restrict__ pl,
                                            size_t idx, float x){
  ushort_t h = f2b(x);
  ph[idx] = h;
  pl[idx] = f2b(x - b2f(h));
}

// full-wave dot: compat(lc,rc) = U[lc].[H(rc);C(rc)] + S[lc] + S[rc]
__device__ __forceinline__ float compat_dot(const float* __restrict__ cU,
                                            const float* __restrict__ cH,
                                            const float* __restrict__ cC,
                                            const float* __restrict__ cS,
                                            int lc, int rc, int lane){
  const float4* U4  = (const float4*)(cU + (size_t)lc*H2);
  const float4* Hr4 = (const float4*)(cH + (size_t)rc*H);
  const float4* Cr4 = (const float4*)(cC + (size_t)rc*H);
  float p = 0.f;
  #pragma unroll
  for (int it=0; it<2; it++){
    float4 u = U4[lane + 64*it], h = Hr4[lane + 64*it];
    p += u.x*h.x + u.y*h.y + u.z*h.z + u.w*h.w;
  }
  #pragma unroll
  for (int it=0; it<2; it++){
    float4 u = U4[128 + lane + 64*it], c = Cr4[lane + 64*it];
    p += u.x*c.x + u.y*c.y + u.z*c.z + u.w*c.w;
  }
  #pragma unroll
  for (int off=32; off>0; off>>=1) p += __shfl_down(p, off);
  return p + cS[lc] + cS[rc];
}

// ---- merged init: split Wi/Ws, transpose+split Wbil, leaves, zero flags/counters
__global__ void k_init(const float* __restrict__ seqt,
                       const float* __restrict__ Wi, const float* __restrict__ Ws,
                       const float* __restrict__ Wbil,
                       ushort_t* __restrict__ WiBh, ushort_t* __restrict__ WiBl,
                       ushort_t* __restrict__ WsBh, ushort_t* __restrict__ WsBl,
                       ushort_t* __restrict__ WbilTh, ushort_t* __restrict__ WbilTl,
                       float* __restrict__ cH, float* __restrict__ cC, float* __restrict__ cS,
                       ushort_t* __restrict__ cHbh, ushort_t* __restrict__ cHbl,
                       ushort_t* __restrict__ cCbh, ushort_t* __restrict__ cCbl,
                       int* __restrict__ flags, int* __restrict__ counters){
  const int blk = blockIdx.x, t = threadIdx.x;
  if (blk < 10240){                       // Wi/Ws split (2*H5*H elems exactly)
    int i = blk*256 + t;
    const int n = H5*H;
    if (i < n) split_store(WiBh, WiBl, i, Wi[i]);
    else       split_store(WsBh, WsBl, i-n, Ws[i-n]);
  } else if (blk < 11264){                // Wbil transpose+split (1024 tiles)
    __shared__ float tile[32][33];
    int tb = blk - 10240;
    int tr = (tb>>5)*32, tc = (tb&31)*32;
    int tx = t & 31, ty = t >> 5;         // 32 x 8
    #pragma unroll
    for (int i=0;i<32;i+=8)
      tile[ty+i][tx] = Wbil[(size_t)(tr+ty+i)*H2 + tc+tx];
    __syncthreads();
    #pragma unroll
    for (int i=0;i<32;i+=8)
      split_store(WbilTh, WbilTl, (size_t)(tc+ty+i)*H2 + tr+tx, tile[tx][ty+i]);
  } else if (blk < 11456){                // leaves (192 blocks)
    int tid = (blk-11264)*256 + t;
    if (tid < NB*NW*H){
      int b = tid/(NW*H); int r = tid%(NW*H); int i = r/H; int d = r%H;
      size_t idx = (size_t)(b*NCELL + i)*H + d;     // coff(0)==0
      float hv = seqt[(size_t)(b*NW+i)*H2 + d];
      float cv = seqt[(size_t)(b*NW+i)*H2 + H + d];
      cH[idx]=hv; cC[idx]=cv;
      split_store(cHbh,cHbl,idx,hv);
      split_store(cCbh,cCbl,idx,cv);
      if (d==0) cS[b*NCELL+i] = 0.f;
    }
  } else {                                // zero flags + queue counters
    int idx = (blk-11456)*256 + t;
    if (idx < NB*NCELL) flags[idx] = 0;
    if (idx < NW) counters[idx] = 0;
  }
}

__device__ __forceinline__ void mfma3(f32x4& acc, bf16x8 ah, bf16x8 al,
                                      bf16x8 bh, bf16x8 bl){
  // split product; lo*lo (~2^-34 rel) dropped
  acc = __builtin_amdgcn_mfma_f32_16x16x32_bf16(ah, bh, acc, 0,0,0);
  acc = __builtin_amdgcn_mfma_f32_16x16x32_bf16(ah, bl, acc, 0,0,0);
  acc = __builtin_amdgcn_mfma_f32_16x16x32_bf16(al, bh, acc, 0,0,0);
}

// proj body for one (jt, m-tile) item on diagonal d (r15's 8-wave K-split)
__device__ __forceinline__ void proj_item(
        const ushort_t* __restrict__ WiBh, const ushort_t* __restrict__ WiBl,
        const ushort_t* __restrict__ WsBh, const ushort_t* __restrict__ WsBl,
        const ushort_t* __restrict__ WbilTh, const ushort_t* __restrict__ WbilTl,
        const float* __restrict__ bi, const float* __restrict__ bs,
        const ushort_t* __restrict__ cHbh, const ushort_t* __restrict__ cHbl,
        const ushort_t* __restrict__ cCbh, const ushort_t* __restrict__ cCbl,
        float* __restrict__ cPI, float* __restrict__ cPS, float* __restrict__ cU,
        f32x4 (*red)[64], int jt, int m0, int d, int P)
{
  const int t = threadIdx.x, wave = t>>6, lane = t&63;
  const int Mtot = NB*P;
  const int nm = min(16, Mtot-m0);

  int kind, j0;
  if (jt < 160){ kind=0; j0 = jt*16; }
  else if (jt < 320){ kind=1; j0 = (jt-160)*16; }
  else { kind=2; j0 = (jt-320)*16; }

  const int r = lane & 15;
  const int q = lane >> 4;

  int mg = m0 + (r < nm ? r : 0);
  const size_t arow = (size_t)((mg/P)*NCELL + coff(d) + mg%P)*H;

  f32x4 acc = {0.f,0.f,0.f,0.f};

  if (kind < 2){
    const ushort_t* bh_ = (kind==0 ? WiBh : WsBh) + (size_t)(j0+r)*H;
    const ushort_t* bl_ = (kind==0 ? WiBl : WsBl) + (size_t)(j0+r)*H;
    const int ks = wave*64 + q*8;
    bf16x8 fah[2], fal[2], fbh[2], fbl[2];
    #pragma unroll
    for (int s=0;s<2;s++){
      const int ko = ks + s*32;
      fah[s] = *(const bf16x8*)(cHbh + arow + ko);
      fal[s] = *(const bf16x8*)(cHbl + arow + ko);
      fbh[s] = *(const bf16x8*)(bh_ + ko);
      fbl[s] = *(const bf16x8*)(bl_ + ko);
    }
    #pragma unroll
    for (int s=0;s<2;s++) mfma3(acc, fah[s], fal[s], fbh[s], fbl[s]);
  } else {
    const ushort_t* bh_ = WbilTh + (size_t)(j0+r)*H2;
    const ushort_t* bl_ = WbilTl + (size_t)(j0+r)*H2;
    const ushort_t* ah_ = (wave<4 ? cHbh : cCbh) + arow;
    const ushort_t* al_ = (wave<4 ? cHbl : cCbl) + arow;
    const int kg0 = wave*128;
    const int ka0 = kg0 & 511;
    bf16x8 fah[4], fal[4], fbh[4], fbl[4];
    #pragma unroll
    for (int s=0;s<4;s++){
      const int so = s*32 + q*8;
      fah[s] = *(const bf16x8*)(ah_ + ka0 + so);
      fal[s] = *(const bf16x8*)(al_ + ka0 + so);
      fbh[s] = *(const bf16x8*)(bh_ + kg0 + so);
      fbl[s] = *(const bf16x8*)(bl_ + kg0 + so);
    }
    #pragma unroll
    for (int s=0;s<4;s++) mfma3(acc, fah[s], fal[s], fbh[s], fbl[s]);
  }

  red[wave][lane] = acc;
  __syncthreads();
  if (wave == 0){
    f32x4 s0=red[0][lane], s1=red[1][lane], s2=red[2][lane], s3=red[3][lane];
    f32x4 s4=red[4][lane], s5=red[5][lane], s6=red[6][lane], s7=red[7][lane];
    f32x4 tot = ((s0+s1)+(s2+s3)) + ((s4+s5)+(s6+s7));   // fixed order
    const int jo = j0 + r;
    float bias = 0.f;
    if (kind==0) bias = bi[jo] + ((jo>=H && jo<3*H)?1.f:0.f);   // ins_bias on [H,3H)
    else if (kind==1) bias = bs[jo];
    #pragma unroll
    for (int reg=0; reg<4; reg++){
      const int m = q*4 + reg;
      if (m < nm){
        const int mg2 = m0 + m;
        const size_t cell = (size_t)((mg2/P)*NCELL + coff(d) + mg2%P);
        const float v = tot[reg];
        if (kind==0)      cPI[cell*H5 + jo] = v + bias;
        else if (kind==1) cPS[cell*H5 + jo] = v + bias;
        else              cU [cell*H2 + jo] = v;
      }
    }
  }
}

// ---- fused per-diagonal step: work-queue of [combine | writers | proj] items.
// Queue order guarantees all combine items are grabbed (by resident blocks)
// before any proj item -> deadlock-free regardless of occupancy/dispatch order.
// Handshake: combine stores -> __syncthreads (vmcnt drain) -> __threadfence
// (agent fence: L2 writeback) -> device-scope atomicAdd(flag). Proj polls
// flag via atomicAdd(,0) (LLC RMW); its data loads are first-touch in this
// dispatch on the consumer L2 -> no stale lines possible.
__global__ void __launch_bounds__(512)
k_step(const ushort_t* __restrict__ WiBh, const ushort_t* __restrict__ WiBl,
       const ushort_t* __restrict__ WsBh, const ushort_t* __restrict__ WsBl,
       const ushort_t* __restrict__ WbilTh, const ushort_t* __restrict__ WbilTl,
       const float* __restrict__ bi, const float* __restrict__ bs,
       float* __restrict__ cH, float* __restrict__ cC, float* __restrict__ cS,
       ushort_t* __restrict__ cHbh, ushort_t* __restrict__ cHbl,
       ushort_t* __restrict__ cCbh, ushort_t* __restrict__ cCbl,
       float* __restrict__ cPI, float* __restrict__ cPS, float* __restrict__ cU,
       const float* __restrict__ compatR, float* __restrict__ compatW,
       int* __restrict__ counters, int* __restrict__ flags,
       int L, int P, int ncomb, int nwrit, int total)
{
  __shared__ int s_item;
  __shared__ float compat_s[32];
  __shared__ float wts_s[32];
  __shared__ float S_s;
  __shared__ float partH[16][32];
  __shared__ float partC[16][32];
  __shared__ f32x4 red[8][64];
  const int t = threadIdx.x;
  const int lane = t & 63;
  const int wave = t >> 6;

  for(;;){
    if (t==0) s_item = atomicAdd(&counters[L], 1);
    __syncthreads();
    const int item = s_item;
    __syncthreads();
    if (item >= total) return;

    if (item < ncomb){
      // ---------------- combine item: (cellid, dg) ----------------
      const int cellid = item >> 4;
      const int dg = item & 15;
      const int b = cellid / P;
      const int left = cellid % P;
      // phase 1: boundary compat inline, interior from precomputed buffer
      if (wave == 0){
        int lc = b*NCELL + left;                       // (left,0) leaf
        int rc = b*NCELL + coff(L-1) + left+1;
        float v = compat_dot(cU, cH, cC, cS, lc, rc, lane);
        if (lane==0) compat_s[0] = v;
      } else if (wave == 1 && L >= 2){
        int lc = b*NCELL + coff(L-1) + left;
        int rc = b*NCELL + left+L;                     // (left+L,0) leaf
        float v = compat_dot(cU, cH, cC, cS, lc, rc, lane);
        if (lane==0) compat_s[L-1] = v;
      }
      if (t >= 1 && t <= L-2) compat_s[t] = compatR[(b*NW + left)*NW + t];
      __syncthreads();
      // phase 2: softmax (serial, thread 0)
      if (t==0){
        float mx = -1e30f;
        for (int k=0;k<L;k++) mx = fmaxf(mx, compat_s[k]);
        float den = 0.f;
        for (int k=0;k<L;k++){ float e = __expf(compat_s[k]-mx); wts_s[k]=e; den+=e; }
        float inv = 1.f/den, S = 0.f;
        for (int k=0;k<L;k++){ wts_s[k]*=inv; S += wts_s[k]*compat_s[k]; }
        S_s = S;
      }
      __syncthreads();
      // phase 3: 32 dims x 16-way k-split
      const int dloc = t & 31;
      const int dim = dg*32 + dloc;
      const int kpar = t >> 5;
      float aH = 0.f, aC = 0.f;
      for (int k=kpar; k<L; k+=16){
        float wk = wts_s[k];
        int lc = b*NCELL + coff(k) + left;
        int rc = b*NCELL + coff(L-1-k) + left+k+1;
        const float* PI = cPI + (size_t)lc*H5;
        const float* PS = cPS + (size_t)rc*H5;
        float p0 = PI[dim]     + PS[dim];
        float p1 = PI[H+dim]   + PS[H+dim];
        float p2 = PI[2*H+dim] + PS[2*H+dim];
        float p3 = PI[3*H+dim] + PS[3*H+dim];
        float p4 = PI[4*H+dim] + PS[4*H+dim];
        float lcv = cC[(size_t)lc*H + dim];
        float rcv = cC[(size_t)rc*H + dim];
        float mem = sigm(p1)*lcv + sigm(p2)*rcv + sigm(p0)*ftanh(p3);
        float h = sigm(p4)*ftanh(mem);
        aH += wk*h; aC += wk*mem;
      }
      if (kpar > 0){ partH[kpar][dloc]=aH; partC[kpar][dloc]=aC; }
      __syncthreads();
      const size_t nc = (size_t)(b*NCELL + coff(L) + left);
      if (kpar == 0){
        #pragma unroll
        for (int q=1;q<16;q++){ aH += partH[q][dloc]; aC += partC[q][dloc]; }
        cH[nc*H + dim] = aH;
        cC[nc*H + dim] = aC;
        split_store(cHbh,cHbl, nc*H + dim, aH);
        split_store(cCbh,cCbl, nc*H + dim, aC);
        if (t==0 && dg==0) cS[nc] = S_s;
      }
      __syncthreads();           // drains all waves' stores (vmcnt) pre-barrier
      if (t==0){
        __threadfence();         // agent fence: L2 writeback -> LLC
        atomicAdd(&flags[nc], 1);
      }
      __syncthreads();
    } else if (item < ncomb + nwrit){
      // ---------------- writer item: 8 compat terms for diag L+1 ----------------
      const int P1 = P-1;
      const int nterm = L-1;
      int tid = (item-ncomb)*8 + wave;
      if (tid < NB*P1*nterm){
        int cell1 = tid / nterm;
        int k = 1 + tid % nterm;
        int b = cell1 / P1, left = cell1 % P1;
        int lc = b*NCELL + coff(k) + left;
        int rc = b*NCELL + coff(L-k) + left+k+1;
        float v = compat_dot(cU, cH, cC, cS, lc, rc, lane);
        if (lane==0) compatW[(b*NW + left)*NW + k] = v;
      }
      __syncthreads();
    } else {
      // ---------------- proj item: (jt, m-tile) for diag L ----------------
      const int pidx = item - ncomb - nwrit;
      const int jt = pidx % 384;
      const int m0 = (pidx / 384) * 16;
      const int Mtot = NB*P;
      const int nm = min(16, Mtot-m0);
      if (t < 16){
        int mg = m0 + (t < nm ? t : 0);
        int cell = (mg/P)*NCELL + coff(L) + mg%P;
        while (atomicAdd(&flags[cell], 0) < 16) {}
      }
      asm volatile("" ::: "memory");
      __syncthreads();
      proj_item(WiBh,WiBl,WsBh,WsBl,WbilTh,WbilTl,bi,bs,
                cHbh,cHbl,cCbh,cCbl,cPI,cPS,cU, red, jt, m0, L, P);
      __syncthreads();
    }
  }
}

// ---- standalone proj for diagonal 0 (leaves; no handshake needed)
__global__ void __launch_bounds__(512)
k_proj0(const ushort_t* __restrict__ WiBh, const ushort_t* __restrict__ WiBl,
        const ushort_t* __restrict__ WsBh, const ushort_t* __restrict__ WsBl,
        const ushort_t* __restrict__ WbilTh, const ushort_t* __restrict__ WbilTl,
        const float* __restrict__ bi, const float* __restrict__ bs,
        const ushort_t* __restrict__ cHbh, const ushort_t* __restrict__ cHbl,
        const ushort_t* __restrict__ cCbh, const ushort_t* __restrict__ cCbl,
        float* __restrict__ cPI, float* __restrict__ cPS, float* __restrict__ cU)
{
  __shared__ f32x4 red[8][64];
  proj_item(WiBh,WiBl,WsBh,WsBl,WbilTh,WbilTl,bi,bs,
            cHbh,cHbl,cCbh,cCbl,cPI,cPS,cU, red,
            blockIdx.x, blockIdx.y*16, 0, NW);
}

// ---- root output: concat(H, C) of cell (0, n-1)
__global__ void k_out(const float* __restrict__ cH, const float* __restrict__ cC,
                      float* __restrict__ out){
  int tid = blockIdx.x*256+threadIdx.x;
  if (tid >= NB*H2) return;
  int b = tid>>10, d = tid&1023;
  int cell = b*NCELL + 299;   // coff(23)+0
  out[tid] = (d<H) ? cH[(size_t)cell*H + d] : cC[(size_t)cell*H + (d-H)];
}

extern "C" void kernel_launch(void* const* d_in, const int* in_sizes, int n_in,
                              void* d_out, int out_size, void* d_ws, size_t ws_size,
                              hipStream_t stream){
  const float* seqt = (const float*)d_in[0];
  const float* Wi   = (const float*)d_in[1];
  const float* bi   = (const float*)d_in[2];
  const float* Ws   = (const float*)d_in[3];
  const float* bs   = (const float*)d_in[4];
  const float* Wbil = (const float*)d_in[5];
  float* out = (float*)d_out;

  float* p = (ws_size >= NEED_BYTES && g_buf == nullptr) ? (float*)d_ws : g_buf;
  float* cH  = p; p += (size_t)NB*NCELL*H;
  float* cC  = p; p += (size_t)NB*NCELL*H;
  float* cS  = p; p += (size_t)NB*NCELL;
  float* cPI = p; p += (size_t)NB*NCELL*H5;
  float* cPS = p; p += (size_t)NB*NCELL*H5;
  float* cU  = p; p += (size_t)NB*NCELL*H2;
  float* compatA = p; p += (size_t)NB*NW*NW;
  float* compatB = p; p += (size_t)NB*NW*NW;
  int* flags    = (int*)p; p += NB*NCELL;
  int* counters = (int*)p; p += NW;
  ushort_t* u = (ushort_t*)p;
  ushort_t* WiBh   = u; u += (size_t)H5*H;
  ushort_t* WiBl   = u; u += (size_t)H5*H;
  ushort_t* WsBh   = u; u += (size_t)H5*H;
  ushort_t* WsBl   = u; u += (size_t)H5*H;
  ushort_t* WbilTh = u; u += (size_t)H2*H2;
  ushort_t* WbilTl = u; u += (size_t)H2*H2;
  ushort_t* cHbh   = u; u += (size_t)NB*NCELL*H;
  ushort_t* cHbl   = u; u += (size_t)NB*NCELL*H;
  ushort_t* cCbh   = u; u += (size_t)NB*NCELL*H;
  ushort_t* cCbl   = u; u += (size_t)NB*NCELL*H;

  k_init<<<11461, 256, 0, stream>>>(seqt, Wi, Ws, Wbil,
      WiBh, WiBl, WsBh, WsBl, WbilTh, WbilTl,
      cH, cC, cS, cHbh, cHbl, cCbh, cCbl, flags, counters);

  k_proj0<<<dim3(384, (NB*NW+15)/16), 512, 0, stream>>>(
      WiBh, WiBl, WsBh, WsBl, WbilTh, WbilTl, bi, bs,
      cHbh, cHbl, cCbh, cCbl, cPI, cPS, cU);

  for (int L=1; L<NW; L++){
    int P = NW - L;
    int ncomb = NB*P*16;
    int P1 = P-1, nterm = L-1;
    int nwrit = (P1>0 && nterm>0) ? (NB*P1*nterm + 7)/8 : 0;
    int nproj = (L < NW-1) ? 384*((NB*P+15)/16) : 0;
    int total = ncomb + nwrit + nproj;
    int grid = total < 1024 ? total : 1024;
    float* bufR = (L&1) ? compatA : compatB;
    float* bufW = (L&1) ? compatB : compatA;
    k_step<<<grid, 512, 0, stream>>>(
        WiBh, WiBl, WsBh, WsBl, WbilTh, WbilTl, bi, bs,
        cH, cC, cS, cHbh, cHbl, cCbh, cCbl, cPI, cPS, cU,
        bufR, bufW, counters, flags, L, P, ncomb, nwrit, total);
  }
  k_out<<<16, 256, 0, stream>>>(cH, cC, out);
}

// Round 17
// 683.735 us; speedup vs baseline: 2.1307x; 2.1307x over previous
//
#include <hip/hip_runtime.h>
#include <math.h>

#define NB 4
#define NW 24
#define H 512
#define H2 1024
#define H5 2560
#define NCELL 300   // n*(n+1)/2 valid cells per batch
#define NEED_BYTES ((size_t)72<<20)

// Private fallback workspace: allocated ONCE at library load (outside
// kernel_launch, so graph capture never sees the hipMalloc). d_ws proved too
// small in round 1 (44.9MB layout corrupted adjacent harness allocations).
static float* g_buf = nullptr;
__attribute__((constructor)) static void dio_alloc_ws(){
  (void)hipMalloc((void**)&g_buf, NEED_BYTES);
}

typedef __attribute__((ext_vector_type(8))) short bf16x8;   // 8 bf16 (4 VGPRs)
typedef __attribute__((ext_vector_type(4))) float f32x4;
typedef unsigned short ushort_t;

__device__ __forceinline__ int coff(int l){ return l*NW - (l*(l-1))/2; }
__device__ __forceinline__ float sigm(float x){ return 1.f/(1.f+__expf(-x)); }
__device__ __forceinline__ float ftanh(float x){ return 1.f - 2.f/(__expf(2.f*x)+1.f); }

__device__ __forceinline__ ushort_t f2b(float x){  // fp32 -> bf16 RNE
  unsigned int u = __float_as_uint(x);
  u += 0x7FFF + ((u>>16)&1);
  return (ushort_t)(u>>16);
}
__device__ __forceinline__ float b2f(ushort_t h){
  return __uint_as_float(((unsigned int)h)<<16);
}
// split-bf16: x ~= hi + lo with effective ~2^-17 relative error
__device__ __forceinline__ void split_store(ushort_t* __restrict__ ph,
                                            ushort_t* __restrict__ pl,
                                            size_t idx, float x){
  ushort_t h = f2b(x);
  ph[idx] = h;
  pl[idx] = f2b(x - b2f(h));
}

// full-wave dot (writers): compat(lc,rc) = U[lc].[H(rc);C(rc)] + S[lc] + S[rc]
__device__ __forceinline__ float compat_dot(const float* __restrict__ cU,
                                            const float* __restrict__ cH,
                                            const float* __restrict__ cC,
                                            const float* __restrict__ cS,
                                            int lc, int rc, int lane){
  const float4* U4  = (const float4*)(cU + (size_t)lc*H2);
  const float4* Hr4 = (const float4*)(cH + (size_t)rc*H);
  const float4* Cr4 = (const float4*)(cC + (size_t)rc*H);
  float p = 0.f;
  #pragma unroll
  for (int it=0; it<2; it++){
    float4 u = U4[lane + 64*it], h = Hr4[lane + 64*it];
    p += u.x*h.x + u.y*h.y + u.z*h.z + u.w*h.w;
  }
  #pragma unroll
  for (int it=0; it<2; it++){
    float4 u = U4[128 + lane + 64*it], c = Cr4[lane + 64*it];
    p += u.x*c.x + u.y*c.y + u.z*c.z + u.w*c.w;
  }
  #pragma unroll
  for (int off=32; off>0; off>>=1) p += __shfl_down(p, off);
  return p + cS[lc] + cS[rc];
}

// ---- merged init: split Wi/Ws, transpose+split Wbil, leaves
__global__ void k_init(const float* __restrict__ seqt,
                       const float* __restrict__ Wi, const float* __restrict__ Ws,
                       const float* __restrict__ Wbil,
                       ushort_t* __restrict__ WiBh, ushort_t* __restrict__ WiBl,
                       ushort_t* __restrict__ WsBh, ushort_t* __restrict__ WsBl,
                       ushort_t* __restrict__ WbilTh, ushort_t* __restrict__ WbilTl,
                       float* __restrict__ cH, float* __restrict__ cC, float* __restrict__ cS,
                       ushort_t* __restrict__ cHbh, ushort_t* __restrict__ cHbl,
                       ushort_t* __restrict__ cCbh, ushort_t* __restrict__ cCbl){
  const int blk = blockIdx.x, t = threadIdx.x;
  if (blk < 10240){                       // Wi/Ws split (2*H5*H elems exactly)
    int i = blk*256 + t;
    const int n = H5*H;
    if (i < n) split_store(WiBh, WiBl, i, Wi[i]);
    else       split_store(WsBh, WsBl, i-n, Ws[i-n]);
  } else if (blk < 11264){                // Wbil transpose+split (1024 tiles)
    __shared__ float tile[32][33];
    int tb = blk - 10240;
    int tr = (tb>>5)*32, tc = (tb&31)*32;
    int tx = t & 31, ty = t >> 5;         // 32 x 8
    #pragma unroll
    for (int i=0;i<32;i+=8)
      tile[ty+i][tx] = Wbil[(size_t)(tr+ty+i)*H2 + tc+tx];
    __syncthreads();
    #pragma unroll
    for (int i=0;i<32;i+=8)
      split_store(WbilTh, WbilTl, (size_t)(tc+ty+i)*H2 + tr+tx, tile[tx][ty+i]);
  } else {                                // leaves (192 blocks)
    int tid = (blk-11264)*256 + t;
    if (tid < NB*NW*H){
      int b = tid/(NW*H); int r = tid%(NW*H); int i = r/H; int d = r%H;
      size_t idx = (size_t)(b*NCELL + i)*H + d;     // coff(0)==0
      float hv = seqt[(size_t)(b*NW+i)*H2 + d];
      float cv = seqt[(size_t)(b*NW+i)*H2 + H + d];
      cH[idx]=hv; cC[idx]=cv;
      split_store(cHbh,cHbl,idx,hv);
      split_store(cCbh,cCbl,idx,cv);
      if (d==0) cS[b*NCELL+i] = 0.f;
    }
  }
}

__device__ __forceinline__ void mfma3(f32x4& acc, bf16x8 ah, bf16x8 al,
                                      bf16x8 bh, bf16x8 bl){
  // split product; lo*lo (~2^-34 rel) dropped
  acc = __builtin_amdgcn_mfma_f32_16x16x32_bf16(ah, bh, acc, 0,0,0);
  acc = __builtin_amdgcn_mfma_f32_16x16x32_bf16(ah, bl, acc, 0,0,0);
  acc = __builtin_amdgcn_mfma_f32_16x16x32_bf16(al, bh, acc, 0,0,0);
}

// ---- MFMA projections, K-split across 8 waves (r15 exact).
// grid.x = 384 j-tiles (0-159: PI, 160-319: PS, 320-383: U), grid.y = m/16.
__global__ void __launch_bounds__(512)
k_projN(const ushort_t* __restrict__ WiBh, const ushort_t* __restrict__ WiBl,
        const ushort_t* __restrict__ WsBh, const ushort_t* __restrict__ WsBl,
        const ushort_t* __restrict__ WbilTh, const ushort_t* __restrict__ WbilTl,
        const float* __restrict__ bi, const float* __restrict__ bs,
        const ushort_t* __restrict__ cHbh, const ushort_t* __restrict__ cHbl,
        const ushort_t* __restrict__ cCbh, const ushort_t* __restrict__ cCbl,
        float* __restrict__ cPI, float* __restrict__ cPS, float* __restrict__ cU,
        int d, int P)
{
  __shared__ f32x4 red[8][64];
  const int t = threadIdx.x, wave = t>>6, lane = t&63;
  const int jt = blockIdx.x;
  const int m0 = blockIdx.y*16;
  const int Mtot = NB*P;
  const int nm = min(16, Mtot-m0);

  int kind, j0;
  if (jt < 160){ kind=0; j0 = jt*16; }
  else if (jt < 320){ kind=1; j0 = (jt-160)*16; }
  else { kind=2; j0 = (jt-320)*16; }

  const int r = lane & 15;   // A row (m) / B row (j) / D col
  const int q = lane >> 4;   // quad: k = q*8 + i

  int mg = m0 + (r < nm ? r : 0);
  const size_t arow = (size_t)((mg/P)*NCELL + coff(d) + mg%P)*H;

  f32x4 acc = {0.f,0.f,0.f,0.f};

  if (kind < 2){
    const ushort_t* bh_ = (kind==0 ? WiBh : WsBh) + (size_t)(j0+r)*H;
    const ushort_t* bl_ = (kind==0 ? WiBl : WsBl) + (size_t)(j0+r)*H;
    const int ks = wave*64 + q*8;           // this wave's K/8 slice
    bf16x8 fah[2], fal[2], fbh[2], fbl[2];
    #pragma unroll
    for (int s=0;s<2;s++){
      const int ko = ks + s*32;
      fah[s] = *(const bf16x8*)(cHbh + arow + ko);
      fal[s] = *(const bf16x8*)(cHbl + arow + ko);
      fbh[s] = *(const bf16x8*)(bh_ + ko);
      fbl[s] = *(const bf16x8*)(bl_ + ko);
    }
    #pragma unroll
    for (int s=0;s<2;s++) mfma3(acc, fah[s], fal[s], fbh[s], fbl[s]);
  } else {
    // U: global k in [0,1024); waves 0-3 -> H chart, 4-7 -> C chart
    const ushort_t* bh_ = WbilTh + (size_t)(j0+r)*H2;
    const ushort_t* bl_ = WbilTl + (size_t)(j0+r)*H2;
    const ushort_t* ah_ = (wave<4 ? cHbh : cCbh) + arow;
    const ushort_t* al_ = (wave<4 ? cHbl : cCbl) + arow;
    const int kg0 = wave*128;               // global k base
    const int ka0 = kg0 & 511;              // chart k base
    bf16x8 fah[4], fal[4], fbh[4], fbl[4];
    #pragma unroll
    for (int s=0;s<4;s++){
      const int so = s*32 + q*8;
      fah[s] = *(const bf16x8*)(ah_ + ka0 + so);
      fal[s] = *(const bf16x8*)(al_ + ka0 + so);
      fbh[s] = *(const bf16x8*)(bh_ + kg0 + so);
      fbl[s] = *(const bf16x8*)(bl_ + kg0 + so);
    }
    #pragma unroll
    for (int s=0;s<4;s++) mfma3(acc, fah[s], fal[s], fbh[s], fbl[s]);
  }

  red[wave][lane] = acc;
  __syncthreads();
  if (wave == 0){
    f32x4 s0=red[0][lane], s1=red[1][lane], s2=red[2][lane], s3=red[3][lane];
    f32x4 s4=red[4][lane], s5=red[5][lane], s6=red[6][lane], s7=red[7][lane];
    f32x4 tot = ((s0+s1)+(s2+s3)) + ((s4+s5)+(s6+s7));   // fixed order
    const int jo = j0 + r;
    float bias = 0.f;
    if (kind==0) bias = bi[jo] + ((jo>=H && jo<3*H)?1.f:0.f);   // ins_bias on [H,3H)
    else if (kind==1) bias = bs[jo];
    #pragma unroll
    for (int reg=0; reg<4; reg++){
      const int m = q*4 + reg;
      if (m < nm){
        const int mg2 = m0 + m;
        const size_t cell = (size_t)((mg2/P)*NCELL + coff(d) + mg2%P);
        const float v = tot[reg];
        if (kind==0)      cPI[cell*H5 + jo] = v + bias;
        else if (kind==1) cPS[cell*H5 + jo] = v + bias;
        else              cU [cell*H2 + jo] = v;
      }
    }
  }
}

// ---- combine diagonal L (512-thread blocks).
// r16 lesson (twice-measured with r10): intra-dispatch producer->consumer
// fences flush L2 -> keep kernel boundaries. This round shortens combine's
// two serial chains instead:
//  - boundary compat dots: 8-load chain -> 2 loads (waves 0-3 = k=0 term,
//    waves 4-7 = k=L-1; one (U,x) float4 pair per thread; LDS fold).
//  - phase 3: 16 dims x 32-way k-split -> exactly 12 loads (L<=23 < 32).
// Interior compat terms from previous dispatch's writer blocks (ping-pong).
// grid.x = NB*P*32 phase blocks + ceil(NB*(P-1)*(L-1)/8) writer blocks.
__global__ void __launch_bounds__(512)
k_combine4(const float* __restrict__ cPI, const float* __restrict__ cPS,
           const float* __restrict__ cU,
           float* __restrict__ cH, float* __restrict__ cC, float* __restrict__ cS,
           ushort_t* __restrict__ cHbh, ushort_t* __restrict__ cHbl,
           ushort_t* __restrict__ cCbh, ushort_t* __restrict__ cCbl,
           const float* __restrict__ compatR, float* __restrict__ compatW,
           int L, int P){
  const int t = threadIdx.x;
  const int lane = t & 63;
  const int wave = t >> 6;
  const int nphase = NB*P*32;
  const int blk = blockIdx.x;

  if (blk >= nphase){
    // writer: one wave per (cell of diag L+1, k in [1,L-1])
    const int P1 = P-1;
    const int nterm = L-1;
    int tid = (blk-nphase)*8 + wave;
    if (P1 > 0 && nterm > 0 && tid < NB*P1*nterm){
      int cell1 = tid / nterm;
      int k = 1 + tid % nterm;
      int b = cell1 / P1, left = cell1 % P1;
      int lc = b*NCELL + coff(k) + left;
      int rc = b*NCELL + coff(L-k) + left+k+1;
      float v = compat_dot(cU, cH, cC, cS, lc, rc, lane);
      if (lane==0) compatW[(b*NW + left)*NW + k] = v;
    }
    return;
  }

  const int cellid = blk >> 5;
  const int dg = blk & 31;            // dim-group: dims [dg*16, dg*16+16)
  const int b = cellid / P;
  const int left = cellid % P;
  __shared__ float compat_s[32];
  __shared__ float wts_s[32];
  __shared__ float S_s;
  __shared__ float bnd[8];
  __shared__ float partH[32][16];
  __shared__ float partC[32][16];

  // phase 1: boundary terms, 2-load chain per thread.
  {
    const int half = t >> 8;          // 0: k=0 term, 1: k=L-1 term
    const int pr = t & 255;           // (U,x) float4-pair index
    int lc, rc;
    if (half==0){ lc = b*NCELL + left;                rc = b*NCELL + coff(L-1) + left+1; }
    else        { lc = b*NCELL + coff(L-1) + left;    rc = b*NCELL + left+L; }
    float pp = 0.f;
    if (half==0 || L>=2){
      float4 u = ((const float4*)(cU + (size_t)lc*H2))[pr];
      float4 x = (pr < 128)
               ? ((const float4*)(cH + (size_t)rc*H))[pr]        // wave-uniform branch
               : ((const float4*)(cC + (size_t)rc*H))[pr-128];
      pp = u.x*x.x + u.y*x.y + u.z*x.z + u.w*x.w;
    }
    #pragma unroll
    for (int off=32; off>0; off>>=1) pp += __shfl_down(pp, off);
    if (lane==0) bnd[wave] = pp;
  }
  if (t >= 1 && t <= L-2) compat_s[t] = compatR[(b*NW + left)*NW + t];
  __syncthreads();
  // phase 2: fold boundaries + softmax (serial, thread 0)
  if (t==0){
    {
      int lc = b*NCELL + left, rc = b*NCELL + coff(L-1) + left+1;
      compat_s[0] = ((bnd[0]+bnd[1])+(bnd[2]+bnd[3])) + cS[lc] + cS[rc];
    }
    if (L >= 2){
      int lc = b*NCELL + coff(L-1) + left, rc = b*NCELL + left+L;
      compat_s[L-1] = ((bnd[4]+bnd[5])+(bnd[6]+bnd[7])) + cS[lc] + cS[rc];
    }
    float mx = -1e30f;
    for (int k=0;k<L;k++) mx = fmaxf(mx, compat_s[k]);
    float den = 0.f;
    for (int k=0;k<L;k++){ float e = __expf(compat_s[k]-mx); wts_s[k]=e; den+=e; }
    float inv = 1.f/den, S = 0.f;
    for (int k=0;k<L;k++){ wts_s[k]*=inv; S += wts_s[k]*compat_s[k]; }
    S_s = S;
  }
  __syncthreads();
  // phase 3: thread owns 1 dim; t>>4 = k-residue (32-way, single k each)
  const int dloc = t & 15;
  const int dim = dg*16 + dloc;
  const int kpar = t >> 4;
  float aH = 0.f, aC = 0.f;
  if (kpar < L){
    const int k = kpar;
    float wk = wts_s[k];
    int lc = b*NCELL + coff(k) + left;
    int rc = b*NCELL + coff(L-1-k) + left+k+1;
    const float* PI = cPI + (size_t)lc*H5;
    const float* PS = cPS + (size_t)rc*H5;
    float p0 = PI[dim]     + PS[dim];
    float p1 = PI[H+dim]   + PS[H+dim];
    float p2 = PI[2*H+dim] + PS[2*H+dim];
    float p3 = PI[3*H+dim] + PS[3*H+dim];
    float p4 = PI[4*H+dim] + PS[4*H+dim];
    float lcv = cC[(size_t)lc*H + dim];
    float rcv = cC[(size_t)rc*H + dim];
    float mem = sigm(p1)*lcv + sigm(p2)*rcv + sigm(p0)*ftanh(p3);
    float h = sigm(p4)*ftanh(mem);
    aH = wk*h; aC = wk*mem;
  }
  if (kpar > 0){ partH[kpar][dloc]=aH; partC[kpar][dloc]=aC; }
  __syncthreads();
  if (kpar == 0){
    #pragma unroll
    for (int q=1;q<32;q++){ aH += partH[q][dloc]; aC += partC[q][dloc]; }
    size_t nc = (size_t)(b*NCELL + coff(L) + left);
    cH[nc*H + dim] = aH;
    cC[nc*H + dim] = aC;
    split_store(cHbh,cHbl, nc*H + dim, aH);
    split_store(cCbh,cCbl, nc*H + dim, aC);
    if (t==0 && dg==0) cS[nc] = S_s;
  }
}

// ---- root output: concat(H, C) of cell (0, n-1)
__global__ void k_out(const float* __restrict__ cH, const float* __restrict__ cC,
                      float* __restrict__ out){
  int tid = blockIdx.x*256+threadIdx.x;
  if (tid >= NB*H2) return;
  int b = tid>>10, d = tid&1023;
  int cell = b*NCELL + 299;   // coff(23)+0
  out[tid] = (d<H) ? cH[(size_t)cell*H + d] : cC[(size_t)cell*H + (d-H)];
}

extern "C" void kernel_launch(void* const* d_in, const int* in_sizes, int n_in,
                              void* d_out, int out_size, void* d_ws, size_t ws_size,
                              hipStream_t stream){
  const float* seqt = (const float*)d_in[0];
  const float* Wi   = (const float*)d_in[1];
  const float* bi   = (const float*)d_in[2];
  const float* Ws   = (const float*)d_in[3];
  const float* bs   = (const float*)d_in[4];
  const float* Wbil = (const float*)d_in[5];
  float* out = (float*)d_out;

  float* p = (ws_size >= NEED_BYTES && g_buf == nullptr) ? (float*)d_ws : g_buf;
  float* cH  = p; p += (size_t)NB*NCELL*H;
  float* cC  = p; p += (size_t)NB*NCELL*H;
  float* cS  = p; p += (size_t)NB*NCELL;
  float* cPI = p; p += (size_t)NB*NCELL*H5;
  float* cPS = p; p += (size_t)NB*NCELL*H5;
  float* cU  = p; p += (size_t)NB*NCELL*H2;
  float* compatA = p; p += (size_t)NB*NW*NW;
  float* compatB = p; p += (size_t)NB*NW*NW;
  ushort_t* u = (ushort_t*)p;
  ushort_t* WiBh   = u; u += (size_t)H5*H;
  ushort_t* WiBl   = u; u += (size_t)H5*H;
  ushort_t* WsBh   = u; u += (size_t)H5*H;
  ushort_t* WsBl   = u; u += (size_t)H5*H;
  ushort_t* WbilTh = u; u += (size_t)H2*H2;
  ushort_t* WbilTl = u; u += (size_t)H2*H2;
  ushort_t* cHbh   = u; u += (size_t)NB*NCELL*H;
  ushort_t* cHbl   = u; u += (size_t)NB*NCELL*H;
  ushort_t* cCbh   = u; u += (size_t)NB*NCELL*H;
  ushort_t* cCbl   = u; u += (size_t)NB*NCELL*H;

  k_init<<<11456, 256, 0, stream>>>(seqt, Wi, Ws, Wbil,
      WiBh, WiBl, WsBh, WsBl, WbilTh, WbilTl,
      cH, cC, cS, cHbh, cHbl, cCbh, cCbl);

  k_projN<<<dim3(384, (NB*NW+15)/16), 512, 0, stream>>>(
      WiBh, WiBl, WsBh, WsBl, WbilTh, WbilTl, bi, bs,
      cHbh, cHbl, cCbh, cCbl, cPI, cPS, cU, 0, NW);
  for (int L=1; L<NW; L++){
    int P = NW - L;
    int P1 = P-1, nterm = L-1;
    int wblk = (P1>0 && nterm>0) ? (NB*P1*nterm + 7)/8 : 0;
    float* bufR = (L&1) ? compatA : compatB;
    float* bufW = (L&1) ? compatB : compatA;
    k_combine4<<<NB*P*32 + wblk, 512, 0, stream>>>(
        cPI, cPS, cU, cH, cC, cS, cHbh, cHbl, cCbh, cCbl,
        bufR, bufW, L, P);
    if (L < NW-1)
      k_projN<<<dim3(384, (NB*P+15)/16), 512, 0, stream>>>(
          WiBh, WiBl, WsBh, WsBl, WbilTh, WbilTl, bi, bs,
          cHbh, cHbl, cCbh, cCbl, cPI, cPS, cU, L, P);
  }
  k_out<<<16, 256, 0, stream>>>(cH, cC, out);
}